// Round 4
// baseline (743.738 us; speedup 1.0000x reference)
//
#include <hip/hip_runtime.h>

// Grouped-dequant GEMM: Y[m,o] = sum_k X[m,k] * W[o,k] * S[o,k/128] + bias[o]
// M=8192, N=O=4096, K=I=4096, G=128. Harness promotes fp16 tensors to f32.
//
// R9: overlap LDS reads with MFMA via one-phase read-ahead. Diagnosis: R6/R7/R8
// (42% MfmaUtil each) all serialized [read-drain | MFMA] inside every phase;
// phase = LDS + MFMA instead of max(LDS, MFMA). Fix: quadrant order
// (m0,n0)->(m1,n0)->(m1,n1)->(m0,n1) with per-tile alternation of which A-reg
// set is "first" makes every phase's reads target registers DISJOINT from that
// phase's MFMA operands, so each fragment is read exactly one phase ahead and
// drains under the MFMA issue window. Reads/phase: 8/4/4/8. One barrier/phase.
//   Q1: lgkm0; rd As(t)[8];        stage A1(t+1);            MFMA(Af,B0r); BAR
//   Q2: lgkm0; rd B1r(t)[4];       stage A0(t+2);            MFMA(As,B0r);
//       vmcnt(4) [publish B(t+1); slack 2-3 phases]; BAR
//   Q3: lgkm0; rd B0r(t+1)[4];     stage B0(t+2);            MFMA(As,B1r);
//       vmcnt(4) [publish A(t+1); slack 2 phases]; BAR
//   Q4: lgkm0; rd Af(t+1)[8] (=As-regs, free after Q3);
//                                  stage B1(t+2);            MFMA(Af,B1r); BAR
// Region safety: every restage lands >=1 barrier after the region's last
// read-issue (A0: read Q1 / staged Q2; B: read Q2 / staged Q3,Q4; A1 of other
// buf: read Q1(t-1) / staged Q1(t)). Tail pair uses vmcnt(0). Frag regs
// AX[8],AY[8],B0r[4],B1r[4] = 96 VGPR, same as R8. LDS chunk-XOR swizzle
// unchanged (slot(r,c)=c^(r&7), pre-swizzled global source, 0 conflicts).

typedef short bf16x8 __attribute__((ext_vector_type(8)));
typedef float f32x4 __attribute__((ext_vector_type(4)));
typedef int   i32x4 __attribute__((ext_vector_type(4)));

#define BM 128
#define BN 128
#define BK 64

__device__ __forceinline__ unsigned pk_bf16_rne(float x, float y) {
    unsigned a = __float_as_uint(x), b = __float_as_uint(y);
    a = a + 0x7FFFu + ((a >> 16) & 1u);          // round-to-nearest-even
    b = b + 0x7FFFu + ((b >> 16) & 1u);
    return (b & 0xFFFF0000u) | (a >> 16);
}

// ---- f32 -> bf16 bulk convert for X (8 f32 -> 16B per thread) ----
__global__ __launch_bounds__(256) void cvt_f32_bf16(
    const float* __restrict__ src, unsigned short* __restrict__ dst, long n)
{
    long i = (long)(blockIdx.x) * blockDim.x + threadIdx.x;   // units of 8 elts
    const long n8 = n >> 3;
    const long stride = (long)gridDim.x * blockDim.x;
    for (; i < n8; i += stride) {
        f32x4 a = *(const f32x4*)(src + i * 8);
        f32x4 b = *(const f32x4*)(src + i * 8 + 4);
        i32x4 o;
        o.x = pk_bf16_rne(a.x, a.y);
        o.y = pk_bf16_rne(a.z, a.w);
        o.z = pk_bf16_rne(b.x, b.y);
        o.w = pk_bf16_rne(b.z, b.w);
        *(i32x4*)(dst + i * 8) = o;
    }
}

// ---- W convert with fused dequant: Wb[o,i] = bf16(W[o,i] * S[o, i>>7]) ----
__global__ __launch_bounds__(256) void cvt_w_scale_bf16(
    const float* __restrict__ src, const float* __restrict__ S,
    unsigned short* __restrict__ dst, int kshift, int groups, long n8)
{
    long i = (long)(blockIdx.x) * blockDim.x + threadIdx.x;
    const long stride = (long)gridDim.x * blockDim.x;
    for (; i < n8; i += stride) {
        const long flat = i << 3;
        const int o = (int)(flat >> kshift);
        const int g = (int)((flat & (((long)1 << kshift) - 1)) >> 7);
        const float s = S[(size_t)o * groups + g];
        f32x4 a = *(const f32x4*)(src + flat);
        f32x4 b = *(const f32x4*)(src + flat + 4);
        i32x4 out;
        out.x = pk_bf16_rne(a.x * s, a.y * s);
        out.y = pk_bf16_rne(a.z * s, a.w * s);
        out.z = pk_bf16_rne(b.x * s, b.y * s);
        out.w = pk_bf16_rne(b.z * s, b.w * s);
        *(i32x4*)(dst + flat) = out;
    }
}

// ---- 256x256 read-ahead-overlapped GEMM ----

// Stage one 128-row half-tile (2 x global_load_lds per thread; each instr
// covers 64 rows: wave w -> rows slab..slab+7, lane l -> row slab+(l>>3),
// swizzled global source chunk (l&7)^(l>>3), linear LDS dest base+lane*16).
#define STAGE_HALF(gbase, ldsbuf, t, h)                                        \
    {                                                                          \
        _Pragma("unroll")                                                      \
        for (int s_ = 0; s_ < 2; ++s_) {                                       \
            const int slab_ = (h) * 128 + s_ * 64 + wave * 8;                  \
            __builtin_amdgcn_global_load_lds(                                  \
                (const __attribute__((address_space(1))) void*)                \
                    ((gbase) + (size_t)slab_ * K + (size_t)(t) * 64),          \
                (__attribute__((address_space(3))) void*)(&(ldsbuf)[slab_ * 64]), \
                16, 0, 0);                                                     \
        }                                                                      \
    }

// 8 A fragments (4 m-tiles x 2 k-steps) for m-half mh of buffer buf.
#define RD_A8(dst, buf, mh)                                                    \
    {                                                                          \
        _Pragma("unroll")                                                      \
        for (int t_ = 0; t_ < 4; ++t_) {                                       \
            dst[t_ * 2 + 0] = *(const bf16x8*)&As_[buf][aBase + ((mh) * 4 + t_) * 1024 + kOff0]; \
            dst[t_ * 2 + 1] = *(const bf16x8*)&As_[buf][aBase + ((mh) * 4 + t_) * 1024 + kOff1]; \
        }                                                                      \
    }

// 4 B fragments (2 n-tiles x 2 k-steps) for n-half nh of buffer buf.
#define RD_B4(dst, buf, nh)                                                    \
    {                                                                          \
        _Pragma("unroll")                                                      \
        for (int t_ = 0; t_ < 2; ++t_) {                                       \
            dst[t_ * 2 + 0] = *(const bf16x8*)&Bs_[buf][bBase + ((nh) * 2 + t_) * 1024 + kOff0]; \
            dst[t_ * 2 + 1] = *(const bf16x8*)&Bs_[buf][bBase + ((nh) * 2 + t_) * 1024 + kOff1]; \
        }                                                                      \
    }

// 16 MFMAs for C-quadrant (mh,nh); same-acc pairs separated by distance 8.
#define MFMA_Q(mh, nh, aA, bB)                                                 \
    {                                                                          \
        __builtin_amdgcn_s_setprio(1);                                         \
        _Pragma("unroll")                                                      \
        for (int ks_ = 0; ks_ < 2; ++ks_)                                      \
            _Pragma("unroll")                                                  \
            for (int t_ = 0; t_ < 4; ++t_)                                     \
                _Pragma("unroll")                                              \
                for (int n_ = 0; n_ < 2; ++n_)                                 \
                    acc[(mh) * 4 + t_][(nh) * 2 + n_] =                        \
                        __builtin_amdgcn_mfma_f32_16x16x32_bf16(               \
                            aA[t_ * 2 + ks_], bB[n_ * 2 + ks_],                \
                            acc[(mh) * 4 + t_][(nh) * 2 + n_], 0, 0, 0);       \
        __builtin_amdgcn_s_setprio(0);                                         \
    }

#define LGKM0 asm volatile("s_waitcnt lgkmcnt(0)" ::: "memory");
#define VMC(n) asm volatile("s_waitcnt vmcnt(" #n ")" ::: "memory");
#define BAR   __builtin_amdgcn_s_barrier();

__global__ __launch_bounds__(512, 2) void gq_gemm256(
    const unsigned short* __restrict__ X,    // M x K bf16 bits
    const unsigned short* __restrict__ W,    // N x K bf16 bits, pre-dequantized
    const float* __restrict__ Bv,            // N
    float* __restrict__ Y,                   // M x N f32
    int M, int N, int K)
{
    __shared__ short As_[2][256 * 64];       // 64 KiB (rows 0-127 = half A0)
    __shared__ short Bs_[2][256 * 64];       // 64 KiB

    const int tid  = threadIdx.x;
    const int wave = tid >> 6;               // 0..7
    const int lane = tid & 63;
    const int wm   = wave >> 2;              // 0..1  (wave tile: 128 x 64)
    const int wn   = wave & 3;               // 0..3
    const int l15  = lane & 15;
    const int quad = lane >> 4;
    const int sw   = l15 & 7;                // row-derived swizzle key

    const int nTilesN = N >> 8;
    int wg = blockIdx.x;
    if ((gridDim.x & 7) == 0) {              // bijective XCD-aware swizzle (T1)
        const int cpx = gridDim.x >> 3;
        wg = (wg & 7) * cpx + (wg >> 3);
    }
    const int bm = wg / nTilesN;
    const int bn = wg % nTilesN;
    const int rowBase = bm << 8;
    const int colBase = bn << 8;

    const int lrow = lane >> 3;
    const int lcol = ((lane & 7) ^ lrow) * 8;              // pre-swizzled source
    const unsigned short* gXbase = X + (size_t)(rowBase + lrow) * K + lcol;
    const unsigned short* gWbase = W + (size_t)(colBase + lrow) * K + lcol;

    const int aBase = (wm * 128 + l15) * 64;
    const int bBase = (wn * 64 + l15) * 64;
    const int kOff0 = (quad ^ sw) * 8;                     // k-step 0 chunk slot
    const int kOff1 = kOff0 ^ 32;                          // k-step 1 (= slot^4)

    const int NT = K >> 6;                                 // 64 K-tiles
    const int niter = NT >> 1;

    f32x4 acc[8][4];
    #pragma unroll
    for (int i = 0; i < 8; ++i)
        #pragma unroll
        for (int j = 0; j < 4; ++j)
            acc[i][j] = (f32x4){0.f, 0.f, 0.f, 0.f};

    bf16x8 AX[8], AY[8], B0r[4], B1r[4];

    // ---- prologue: tile0 fully staged (oldest), then A0(1),B0(1),B1(1) ----
    STAGE_HALF(gXbase, As_[0], 0, 0);                      // A0(0)
    STAGE_HALF(gXbase, As_[0], 0, 1);                      // A1(0)
    STAGE_HALF(gWbase, Bs_[0], 0, 0);                      // B0(0)
    STAGE_HALF(gWbase, Bs_[0], 0, 1);                      // B1(0)
    STAGE_HALF(gXbase, As_[1], 1, 0);                      // A0(1)
    STAGE_HALF(gWbase, Bs_[1], 1, 0);                      // B0(1)
    STAGE_HALF(gWbase, Bs_[1], 1, 1);                      // B1(1)
    VMC(6);                                                // tile0 landed
    BAR;
    RD_A8(AX, 0, 0);                                       // Af(0) = A(0,mh0)
    RD_B4(B0r, 0, 0);                                      // B(0,nh0)

    #pragma unroll 1
    for (int it = 0; it < niter; ++it) {
        const int u0 = it << 1;
        const bool gnext = (it + 1) < niter;

        // ===== tile u0 (buf0, Af=AX, As=AY) =====
        // Q1 (m0,n0)
        LGKM0;
        RD_A8(AY, 0, 1);                                   // As(u0)=A(u0,mh1)
        STAGE_HALF(gXbase, As_[1], u0 + 1, 1);             // A1(u0+1)
        MFMA_Q(0, 0, AX, B0r);
        BAR;
        // Q2 (m1,n0)
        LGKM0;
        RD_B4(B1r, 0, 1);                                  // B(u0,nh1)
        if (gnext) STAGE_HALF(gXbase, As_[0], u0 + 2, 0);  // A0(u0+2)
        MFMA_Q(1, 0, AY, B0r);
        if (gnext) { VMC(4); } else { VMC(0); }            // publish B(u0+1)
        BAR;
        // Q3 (m1,n1)
        LGKM0;
        RD_B4(B0r, 1, 0);                                  // B(u0+1,nh0)
        if (gnext) STAGE_HALF(gWbase, Bs_[0], u0 + 2, 0);  // B0(u0+2)
        MFMA_Q(1, 1, AY, B1r);
        if (gnext) { VMC(4); } else { VMC(0); }            // publish A(u0+1)
        BAR;
        // Q4 (m0,n1)
        LGKM0;
        RD_A8(AY, 1, 0);                                   // Af(u0+1)=A(u0+1,mh0)
        if (gnext) STAGE_HALF(gWbase, Bs_[0], u0 + 2, 1);  // B1(u0+2)
        MFMA_Q(0, 1, AX, B1r);
        BAR;

        // ===== tile u1 = u0+1 (buf1, Af=AY, As=AX) =====
        // Q1 (m0,n0)
        LGKM0;
        RD_A8(AX, 1, 1);                                   // As(u1)=A(u1,mh1)
        if (gnext) STAGE_HALF(gXbase, As_[0], u0 + 2, 1);  // A1(u0+2)
        MFMA_Q(0, 0, AY, B0r);
        BAR;
        // Q2 (m1,n0)
        LGKM0;
        RD_B4(B1r, 1, 1);                                  // B(u1,nh1)
        if (gnext) STAGE_HALF(gXbase, As_[1], u0 + 3, 0);  // A0(u0+3)
        MFMA_Q(1, 0, AX, B0r);
        if (gnext) { VMC(4); } else { VMC(0); }            // publish B(u0+2)
        BAR;
        // Q3 (m1,n1)
        LGKM0;
        if (gnext) {
            RD_B4(B0r, 0, 0);                              // B(u0+2,nh0)
            STAGE_HALF(gWbase, Bs_[1], u0 + 3, 0);         // B0(u0+3)
        }
        MFMA_Q(1, 1, AX, B1r);
        if (gnext) { VMC(4); } else { VMC(0); }            // publish A(u0+2)
        BAR;
        // Q4 (m0,n1)
        LGKM0;
        if (gnext) {
            RD_A8(AX, 0, 0);                               // Af(u0+2)=A(u0+2,mh0)
            STAGE_HALF(gWbase, Bs_[1], u0 + 3, 1);         // B1(u0+3)
        }
        MFMA_Q(0, 1, AY, B1r);
        BAR;
    }

    // ---- epilogue: Y = acc + bias ----
    #pragma unroll
    for (int nt = 0; nt < 4; ++nt) {
        const int col = colBase + wn * 64 + nt * 16 + l15;
        const float bf = Bv[col];
        #pragma unroll
        for (int mt = 0; mt < 8; ++mt) {
            const int row0 = rowBase + wm * 128 + mt * 16 + quad * 4;
            #pragma unroll
            for (int r = 0; r < 4; ++r)
                Y[(size_t)(row0 + r) * N + col] = acc[mt][nt][r] + bf;
        }
    }
}

// ---- Path B fallback: f32 inputs inline-converted, 128^2 tile (unchanged) ----
__global__ __launch_bounds__(256) void gq_gemm_f32in(
    const float* __restrict__ Xf, const float* __restrict__ Wf,
    const float* __restrict__ S, const float* __restrict__ Bv,
    float* __restrict__ Y, int M, int N, int K)
{
    __shared__ short As[BM * BK];
    __shared__ short Bs[BN * BK];

    const int tid  = threadIdx.x;
    const int wave = tid >> 6;
    const int lane = tid & 63;
    const int wm   = wave >> 1;
    const int wn   = wave & 1;
    const int l15  = lane & 15;
    const int quad = lane >> 4;
    const int sw   = l15 & 7;

    const int nTilesN = N / BN;
    const int bm = blockIdx.x / nTilesN;
    const int bn = blockIdx.x % nTilesN;
    const int rowBase = bm * BM;
    const int colBase = bn * BN;
    const int srow  = tid >> 3;
    const int scol  = (tid & 7) * 8;
    const int sslot = ((tid & 7) ^ (srow & 7)) * 8;
    const int groups = K >> 7;

    f32x4 acc[4][4];
    #pragma unroll
    for (int i = 0; i < 4; ++i)
        #pragma unroll
        for (int j = 0; j < 4; ++j)
            acc[i][j] = (f32x4){0.f, 0.f, 0.f, 0.f};

    float t_prev[4] = {1.f, 1.f, 1.f, 1.f};

    for (int k0 = 0; k0 < K; k0 += BK) {
        i32x4 ra[4], rb[4];
        #pragma unroll
        for (int i = 0; i < 4; ++i) {
            const int row = i * 32 + srow;
            const float* gA = Xf + (size_t)(rowBase + row) * K + (k0 + scol);
            const float* gB = Wf + (size_t)(colBase + row) * K + (k0 + scol);
            f32x4 a0 = *(const f32x4*)gA, a1 = *(const f32x4*)(gA + 4);
            f32x4 b0 = *(const f32x4*)gB, b1 = *(const f32x4*)(gB + 4);
            ra[i].x = pk_bf16_rne(a0.x, a0.y); ra[i].y = pk_bf16_rne(a0.z, a0.w);
            ra[i].z = pk_bf16_rne(a1.x, a1.y); ra[i].w = pk_bf16_rne(a1.z, a1.w);
            rb[i].x = pk_bf16_rne(b0.x, b0.y); rb[i].y = pk_bf16_rne(b0.z, b0.w);
            rb[i].z = pk_bf16_rne(b1.x, b1.y); rb[i].w = pk_bf16_rne(b1.z, b1.w);
        }
        if ((k0 & 127) == 0) {
            const int g = k0 >> 7;
            float r[4];
            #pragma unroll
            for (int nt = 0; nt < 4; ++nt) {
                const int o = colBase + wn * 64 + nt * 16 + l15;
                const float t_cur = S[(size_t)o * groups + g];
                r[nt] = t_prev[nt] / t_cur;
                t_prev[nt] = t_cur;
            }
            #pragma unroll
            for (int mt = 0; mt < 4; ++mt)
                #pragma unroll
                for (int nt = 0; nt < 4; ++nt)
                    #pragma unroll
                    for (int e = 0; e < 4; ++e)
                        acc[mt][nt][e] *= r[nt];
        }
        __syncthreads();
        #pragma unroll
        for (int i = 0; i < 4; ++i) {
            const int row = i * 32 + srow;
            *(i32x4*)&As[row * BK + sslot] = ra[i];
            *(i32x4*)&Bs[row * BK + sslot] = rb[i];
        }
        __syncthreads();
        #pragma unroll
        for (int ks = 0; ks < 2; ++ks) {
            const int kb = ((ks * 4 + quad) ^ sw) * 8;
            bf16x8 a[4], b[4];
            #pragma unroll
            for (int t = 0; t < 4; ++t)
                a[t] = *(const bf16x8*)&As[(wm * 64 + t * 16 + l15) * BK + kb];
            #pragma unroll
            for (int t = 0; t < 4; ++t)
                b[t] = *(const bf16x8*)&Bs[(wn * 64 + t * 16 + l15) * BK + kb];
            #pragma unroll
            for (int mt = 0; mt < 4; ++mt)
                #pragma unroll
                for (int nt = 0; nt < 4; ++nt)
                    acc[mt][nt] = __builtin_amdgcn_mfma_f32_16x16x32_bf16(
                        a[mt], b[nt], acc[mt][nt], 0, 0, 0);
        }
    }
    #pragma unroll
    for (int nt = 0; nt < 4; ++nt) {
        const int col = colBase + wn * 64 + nt * 16 + l15;
        const float tl = t_prev[nt];
        const float bf = Bv[col];
        #pragma unroll
        for (int mt = 0; mt < 4; ++mt) {
            const int row0 = rowBase + wm * 64 + mt * 16 + quad * 4;
            #pragma unroll
            for (int r = 0; r < 4; ++r)
                Y[(size_t)(row0 + r) * N + col] = acc[mt][nt][r] * tl + bf;
        }
    }
}

extern "C" void kernel_launch(void* const* d_in, const int* in_sizes, int n_in,
                              void* d_out, int out_size, void* d_ws, size_t ws_size,
                              hipStream_t stream) {
    const float* X  = (const float*)d_in[0];   // x      (B,S,I)  f32
    const float* W  = (const float*)d_in[1];   // weight (O,I)    f32
    const float* S  = (const float*)d_in[2];   // scales (O,I/G)  f32
    const float* Bv = (const float*)d_in[3];   // bias   (O,)     f32
    float* Y = (float*)d_out;

    const int O = in_sizes[3];                 // 4096
    const int K = in_sizes[1] / O;             // 4096
    const int M = in_sizes[0] / K;             // 8192

    const size_t nX = (size_t)M * K, nW = (size_t)O * K;
    const size_t wsNeeded = (nX + nW) * sizeof(unsigned short);
    const bool shapeOK = (M % 256 == 0) && (O % 256 == 0) && (K % 128 == 0) &&
                         ((K & (K - 1)) == 0);

    if (ws_size >= wsNeeded && shapeOK) {
        unsigned short* Xb = (unsigned short*)d_ws;
        unsigned short* Wb = Xb + nX;
        const int kshift = __builtin_ctz((unsigned)K);
        cvt_f32_bf16<<<(int)(nX >> 11), 256, 0, stream>>>(X, Xb, (long)nX);
        cvt_w_scale_bf16<<<(int)(nW >> 11), 256, 0, stream>>>(
            W, S, Wb, kshift, K >> 7, (long)(nW >> 3));
        gq_gemm256<<<dim3((M >> 8) * (O >> 8)), dim3(512), 0, stream>>>(
            Xb, Wb, Bv, Y, M, O, K);
    } else {
        gq_gemm_f32in<<<dim3((M / BM) * (O / BN)), 256, 0, stream>>>(
            X, W, S, Bv, Y, M, O, K);
    }
}

// Round 5
// 647.563 us; speedup vs baseline: 1.1485x; 1.1485x over previous
//
#include <hip/hip_runtime.h>

// Grouped-dequant GEMM: Y[m,o] = sum_k X[m,k] * W[o,k] * S[o,k/128] + bias[o]
// M=8192, N=O=4096, K=I=4096, G=128. Harness promotes fp16 tensors to f32.
//
// R10: counted-lgkm read-ahead (the m201 "lgkmcnt(8) if 12 reads" mechanism).
// R8 post-mortem: 5231 cyc/K-tile = MFMA 2483 + LDS 2270 + barriers, an exact
// zero-overlap sum -- its per-phase lgkmcnt(0) serialized read-drain | MFMA.
// R9 tried read-ahead but spilled (conditional register reads under the
// 256-reg cap; WRITE_SIZE 157->396 MB). R10 keeps R8's arrays/macros and makes
// every read UNCONDITIONAL (tail reads touch stale LDS, never consumed).
//
// Per tile t (buf c=t&1; A-frag roles alternate per tile: even E=AX,O=AY):
//  q0: rd aO(t)[8];        lgkm(8);                     BAR; MFMA(E,bN0); BAR
//  q1: rd bN1(t)[4];       lgkm(4); vmcnt(0)=publish;   BAR; MFMA(O,bN0); BAR
//  q2: rd bN0(t+1)[4];     lgkm(4); stage A0,A1(t+2);   BAR; MFMA(O,bN1); BAR
//  q3: rd aE(t+1)[8];               stage B0,B1(t+2);   BAR; MFMA(E,bN1); BAR
// Every MFMA operand is read >=1 full phase earlier, so its drain hides under
// the previous MFMA window; the counted lgkm leaves only the just-issued
// (next-phase) reads outstanding. Stage safety: a region's last reads are
// drained by a per-wave lgkm + barrier BEFORE any wave issues the restage
// (A sealed by q1's lgkm(4)+BAR -> staged q2; B sealed by q2's lgkm(4)+BAR ->
// staged q3). Publish tile t+1 at q1(t): outstanding = exactly its 4 halves,
// issued q2/q3(t-1), 2-3 phases (>=1300cyc) earlier -> vmcnt(0) is ~free.
// LDS chunk-XOR swizzle unchanged (slot(r,c)=c^(r&7), pre-swizzled global
// source, linear DMA dest, swizzled ds_read_b128; measured 0 conflicts).

typedef short bf16x8 __attribute__((ext_vector_type(8)));
typedef float f32x4 __attribute__((ext_vector_type(4)));
typedef int   i32x4 __attribute__((ext_vector_type(4)));

#define BM 128
#define BN 128
#define BK 64

__device__ __forceinline__ unsigned pk_bf16_rne(float x, float y) {
    unsigned a = __float_as_uint(x), b = __float_as_uint(y);
    a = a + 0x7FFFu + ((a >> 16) & 1u);          // round-to-nearest-even
    b = b + 0x7FFFu + ((b >> 16) & 1u);
    return (b & 0xFFFF0000u) | (a >> 16);
}

// ---- f32 -> bf16 bulk convert for X (8 f32 -> 16B per thread) ----
__global__ __launch_bounds__(256) void cvt_f32_bf16(
    const float* __restrict__ src, unsigned short* __restrict__ dst, long n)
{
    long i = (long)(blockIdx.x) * blockDim.x + threadIdx.x;   // units of 8 elts
    const long n8 = n >> 3;
    const long stride = (long)gridDim.x * blockDim.x;
    for (; i < n8; i += stride) {
        f32x4 a = *(const f32x4*)(src + i * 8);
        f32x4 b = *(const f32x4*)(src + i * 8 + 4);
        i32x4 o;
        o.x = pk_bf16_rne(a.x, a.y);
        o.y = pk_bf16_rne(a.z, a.w);
        o.z = pk_bf16_rne(b.x, b.y);
        o.w = pk_bf16_rne(b.z, b.w);
        *(i32x4*)(dst + i * 8) = o;
    }
}

// ---- W convert with fused dequant: Wb[o,i] = bf16(W[o,i] * S[o, i>>7]) ----
__global__ __launch_bounds__(256) void cvt_w_scale_bf16(
    const float* __restrict__ src, const float* __restrict__ S,
    unsigned short* __restrict__ dst, int kshift, int groups, long n8)
{
    long i = (long)(blockIdx.x) * blockDim.x + threadIdx.x;
    const long stride = (long)gridDim.x * blockDim.x;
    for (; i < n8; i += stride) {
        const long flat = i << 3;
        const int o = (int)(flat >> kshift);
        const int g = (int)((flat & (((long)1 << kshift) - 1)) >> 7);
        const float s = S[(size_t)o * groups + g];
        f32x4 a = *(const f32x4*)(src + flat);
        f32x4 b = *(const f32x4*)(src + flat + 4);
        i32x4 out;
        out.x = pk_bf16_rne(a.x * s, a.y * s);
        out.y = pk_bf16_rne(a.z * s, a.w * s);
        out.z = pk_bf16_rne(b.x * s, b.y * s);
        out.w = pk_bf16_rne(b.z * s, b.w * s);
        *(i32x4*)(dst + flat) = out;
    }
}

// ---- 256x256 counted-lgkm read-ahead GEMM ----

// Stage one 128-row half-tile (2 x global_load_lds per thread; each instr
// covers 64 rows: wave w -> rows slab..slab+7, lane l -> row slab+(l>>3),
// swizzled global source chunk (l&7)^(l>>3), linear LDS dest base+lane*16).
#define STAGE_HALF(gbase, ldsbuf, t, h)                                        \
    {                                                                          \
        _Pragma("unroll")                                                      \
        for (int s_ = 0; s_ < 2; ++s_) {                                       \
            const int slab_ = (h) * 128 + s_ * 64 + wave * 8;                  \
            __builtin_amdgcn_global_load_lds(                                  \
                (const __attribute__((address_space(1))) void*)                \
                    ((gbase) + (size_t)slab_ * K + (size_t)(t) * 64),          \
                (__attribute__((address_space(3))) void*)(&(ldsbuf)[slab_ * 64]), \
                16, 0, 0);                                                     \
        }                                                                      \
    }

// 8 A fragments (4 m-tiles x 2 k-steps) for wave-local m-half mh of buffer buf.
#define RD_A8(dst, buf, mh)                                                    \
    {                                                                          \
        _Pragma("unroll")                                                      \
        for (int t_ = 0; t_ < 4; ++t_) {                                       \
            dst[t_ * 2 + 0] = *(const bf16x8*)&As_[buf][aBase + ((mh) * 4 + t_) * 1024 + kOff0]; \
            dst[t_ * 2 + 1] = *(const bf16x8*)&As_[buf][aBase + ((mh) * 4 + t_) * 1024 + kOff1]; \
        }                                                                      \
    }

// 4 B fragments (2 n-tiles x 2 k-steps) for wave-local n-half nh of buffer buf.
#define RD_B4(dst, buf, nh)                                                    \
    {                                                                          \
        _Pragma("unroll")                                                      \
        for (int t_ = 0; t_ < 2; ++t_) {                                       \
            dst[t_ * 2 + 0] = *(const bf16x8*)&Bs_[buf][bBase + ((nh) * 2 + t_) * 1024 + kOff0]; \
            dst[t_ * 2 + 1] = *(const bf16x8*)&Bs_[buf][bBase + ((nh) * 2 + t_) * 1024 + kOff1]; \
        }                                                                      \
    }

// 16 MFMAs for C-quadrant (mh,nh); same-acc pairs separated by distance 8.
#define MFMA_Q(mh, nh, aA, bB)                                                 \
    {                                                                          \
        __builtin_amdgcn_s_setprio(1);                                         \
        _Pragma("unroll")                                                      \
        for (int ks_ = 0; ks_ < 2; ++ks_)                                      \
            _Pragma("unroll")                                                  \
            for (int t_ = 0; t_ < 4; ++t_)                                     \
                _Pragma("unroll")                                              \
                for (int n_ = 0; n_ < 2; ++n_)                                 \
                    acc[(mh) * 4 + t_][(nh) * 2 + n_] =                        \
                        __builtin_amdgcn_mfma_f32_16x16x32_bf16(               \
                            aA[t_ * 2 + ks_], bB[n_ * 2 + ks_],                \
                            acc[(mh) * 4 + t_][(nh) * 2 + n_], 0, 0, 0);       \
        __builtin_amdgcn_s_setprio(0);                                         \
    }

#define LGKM(n) asm volatile("s_waitcnt lgkmcnt(" #n ")" ::: "memory");
#define VMC(n)  asm volatile("s_waitcnt vmcnt(" #n ")" ::: "memory");
#define BAR     __builtin_amdgcn_s_barrier();

__global__ __launch_bounds__(512, 2) void gq_gemm256(
    const unsigned short* __restrict__ X,    // M x K bf16 bits
    const unsigned short* __restrict__ W,    // N x K bf16 bits, pre-dequantized
    const float* __restrict__ Bv,            // N
    float* __restrict__ Y,                   // M x N f32
    int M, int N, int K)
{
    __shared__ short As_[2][256 * 64];       // 64 KiB (rows 0-127 = half A0)
    __shared__ short Bs_[2][256 * 64];       // 64 KiB

    const int tid  = threadIdx.x;
    const int wave = tid >> 6;               // 0..7
    const int lane = tid & 63;
    const int wm   = wave >> 2;              // 0..1  (wave tile: 128 x 64)
    const int wn   = wave & 3;               // 0..3
    const int l15  = lane & 15;
    const int quad = lane >> 4;
    const int sw   = l15 & 7;                // row-derived swizzle key

    const int nTilesN = N >> 8;
    int wg = blockIdx.x;
    if ((gridDim.x & 7) == 0) {              // bijective XCD-aware swizzle (T1)
        const int cpx = gridDim.x >> 3;
        wg = (wg & 7) * cpx + (wg >> 3);
    }
    const int bm = wg / nTilesN;
    const int bn = wg % nTilesN;
    const int rowBase = bm << 8;
    const int colBase = bn << 8;

    const int lrow = lane >> 3;
    const int lcol = ((lane & 7) ^ lrow) * 8;              // pre-swizzled source
    const unsigned short* gXbase = X + (size_t)(rowBase + lrow) * K + lcol;
    const unsigned short* gWbase = W + (size_t)(colBase + lrow) * K + lcol;

    const int aBase = (wm * 128 + l15) * 64;
    const int bBase = (wn * 64 + l15) * 64;
    const int kOff0 = (quad ^ sw) * 8;                     // k-step 0 chunk slot
    const int kOff1 = kOff0 ^ 32;                          // k-step 1 (= slot^4)

    const int NT = K >> 6;                                 // 64 K-tiles
    const int niter = NT >> 1;

    f32x4 acc[8][4];
    #pragma unroll
    for (int i = 0; i < 8; ++i)
        #pragma unroll
        for (int j = 0; j < 4; ++j)
            acc[i][j] = (f32x4){0.f, 0.f, 0.f, 0.f};

    bf16x8 AX[8], AY[8], bN0[4], bN1[4];

    // ---- prologue: tiles 0 and 1 fully staged; preload q0(0) operands ----
    STAGE_HALF(gXbase, As_[0], 0, 0);                      // A0(0)
    STAGE_HALF(gXbase, As_[0], 0, 1);                      // A1(0)
    STAGE_HALF(gWbase, Bs_[0], 0, 0);                      // B0(0)
    STAGE_HALF(gWbase, Bs_[0], 0, 1);                      // B1(0)
    STAGE_HALF(gXbase, As_[1], 1, 0);                      // A0(1)
    STAGE_HALF(gXbase, As_[1], 1, 1);                      // A1(1)
    STAGE_HALF(gWbase, Bs_[1], 1, 0);                      // B0(1)
    STAGE_HALF(gWbase, Bs_[1], 1, 1);                      // B1(1)
    VMC(4);                                                // tile0 landed
    BAR;
    RD_A8(AX, 0, 0);                                       // aE(0)
    RD_B4(bN0, 0, 0);                                      // bN0(0)

    #pragma unroll 1
    for (int it = 0; it < niter; ++it) {
        const int u0 = it << 1;                            // even tile (buf0)
        const bool gnext = (it + 1) < niter;               // u0+2 / u0+3 < NT

        // ========== tile u0 (buf0, E=AX, O=AY) ==========
        // q0 (m0,n0)
        RD_A8(AY, 0, 1);                                   // aO(u0)
        LGKM(8);
        BAR; MFMA_Q(0, 0, AX, bN0); BAR;
        // q1 (m1,n0)
        RD_B4(bN1, 0, 1);                                  // bN1(u0)
        LGKM(4);
        VMC(0);                                            // publish tile u0+1
        BAR; MFMA_Q(1, 0, AY, bN0); BAR;
        // q2 (m1,n1)
        RD_B4(bN0, 1, 0);                                  // bN0(u0+1)
        LGKM(4);
        if (gnext) {
            STAGE_HALF(gXbase, As_[0], u0 + 2, 0);         // A0(u0+2)
            STAGE_HALF(gXbase, As_[0], u0 + 2, 1);         // A1(u0+2)
        }
        BAR; MFMA_Q(1, 1, AY, bN1); BAR;
        // q3 (m0,n1)
        RD_A8(AY, 1, 0);                                   // aE(u0+1)
        if (gnext) {
            STAGE_HALF(gWbase, Bs_[0], u0 + 2, 0);         // B0(u0+2)
            STAGE_HALF(gWbase, Bs_[0], u0 + 2, 1);         // B1(u0+2)
        }
        BAR; MFMA_Q(0, 1, AX, bN1); BAR;

        // ========== tile u1 = u0+1 (buf1, E=AY, O=AX) ==========
        // q0 (m0,n0)
        RD_A8(AX, 1, 1);                                   // aO(u1)
        LGKM(8);
        BAR; MFMA_Q(0, 0, AY, bN0); BAR;
        // q1 (m1,n0)
        RD_B4(bN1, 1, 1);                                  // bN1(u1)
        LGKM(4);
        VMC(0);                                            // publish tile u0+2
        BAR; MFMA_Q(1, 0, AX, bN0); BAR;
        // q2 (m1,n1)
        RD_B4(bN0, 0, 0);                                  // bN0(u0+2) [stale if last]
        LGKM(4);
        if (gnext) {
            STAGE_HALF(gXbase, As_[1], u0 + 3, 0);         // A0(u0+3)
            STAGE_HALF(gXbase, As_[1], u0 + 3, 1);         // A1(u0+3)
        }
        BAR; MFMA_Q(1, 1, AX, bN1); BAR;
        // q3 (m0,n1)
        RD_A8(AX, 0, 0);                                   // aE(u0+2) [stale if last]
        if (gnext) {
            STAGE_HALF(gWbase, Bs_[1], u0 + 3, 0);         // B0(u0+3)
            STAGE_HALF(gWbase, Bs_[1], u0 + 3, 1);         // B1(u0+3)
        }
        BAR; MFMA_Q(0, 1, AY, bN1); BAR;
    }

    // ---- epilogue: Y = acc + bias ----
    #pragma unroll
    for (int nt = 0; nt < 4; ++nt) {
        const int col = colBase + wn * 64 + nt * 16 + l15;
        const float bf = Bv[col];
        #pragma unroll
        for (int mt = 0; mt < 8; ++mt) {
            const int row0 = rowBase + wm * 128 + mt * 16 + quad * 4;
            #pragma unroll
            for (int r = 0; r < 4; ++r)
                Y[(size_t)(row0 + r) * N + col] = acc[mt][nt][r] + bf;
        }
    }
}

// ---- Path B fallback: f32 inputs inline-converted, 128^2 tile (unchanged) ----
__global__ __launch_bounds__(256) void gq_gemm_f32in(
    const float* __restrict__ Xf, const float* __restrict__ Wf,
    const float* __restrict__ S, const float* __restrict__ Bv,
    float* __restrict__ Y, int M, int N, int K)
{
    __shared__ short As[BM * BK];
    __shared__ short Bs[BN * BK];

    const int tid  = threadIdx.x;
    const int wave = tid >> 6;
    const int lane = tid & 63;
    const int wm   = wave >> 1;
    const int wn   = wave & 1;
    const int l15  = lane & 15;
    const int quad = lane >> 4;
    const int sw   = l15 & 7;

    const int nTilesN = N / BN;
    const int bm = blockIdx.x / nTilesN;
    const int bn = blockIdx.x % nTilesN;
    const int rowBase = bm * BM;
    const int colBase = bn * BN;
    const int srow  = tid >> 3;
    const int scol  = (tid & 7) * 8;
    const int sslot = ((tid & 7) ^ (srow & 7)) * 8;
    const int groups = K >> 7;

    f32x4 acc[4][4];
    #pragma unroll
    for (int i = 0; i < 4; ++i)
        #pragma unroll
        for (int j = 0; j < 4; ++j)
            acc[i][j] = (f32x4){0.f, 0.f, 0.f, 0.f};

    float t_prev[4] = {1.f, 1.f, 1.f, 1.f};

    for (int k0 = 0; k0 < K; k0 += BK) {
        i32x4 ra[4], rb[4];
        #pragma unroll
        for (int i = 0; i < 4; ++i) {
            const int row = i * 32 + srow;
            const float* gA = Xf + (size_t)(rowBase + row) * K + (k0 + scol);
            const float* gB = Wf + (size_t)(colBase + row) * K + (k0 + scol);
            f32x4 a0 = *(const f32x4*)gA, a1 = *(const f32x4*)(gA + 4);
            f32x4 b0 = *(const f32x4*)gB, b1 = *(const f32x4*)(gB + 4);
            ra[i].x = pk_bf16_rne(a0.x, a0.y); ra[i].y = pk_bf16_rne(a0.z, a0.w);
            ra[i].z = pk_bf16_rne(a1.x, a1.y); ra[i].w = pk_bf16_rne(a1.z, a1.w);
            rb[i].x = pk_bf16_rne(b0.x, b0.y); rb[i].y = pk_bf16_rne(b0.z, b0.w);
            rb[i].z = pk_bf16_rne(b1.x, b1.y); rb[i].w = pk_bf16_rne(b1.z, b1.w);
        }
        if ((k0 & 127) == 0) {
            const int g = k0 >> 7;
            float r[4];
            #pragma unroll
            for (int nt = 0; nt < 4; ++nt) {
                const int o = colBase + wn * 64 + nt * 16 + l15;
                const float t_cur = S[(size_t)o * groups + g];
                r[nt] = t_prev[nt] / t_cur;
                t_prev[nt] = t_cur;
            }
            #pragma unroll
            for (int mt = 0; mt < 4; ++mt)
                #pragma unroll
                for (int nt = 0; nt < 4; ++nt)
                    #pragma unroll
                    for (int e = 0; e < 4; ++e)
                        acc[mt][nt][e] *= r[nt];
        }
        __syncthreads();
        #pragma unroll
        for (int i = 0; i < 4; ++i) {
            const int row = i * 32 + srow;
            *(i32x4*)&As[row * BK + sslot] = ra[i];
            *(i32x4*)&Bs[row * BK + sslot] = rb[i];
        }
        __syncthreads();
        #pragma unroll
        for (int ks = 0; ks < 2; ++ks) {
            const int kb = ((ks * 4 + quad) ^ sw) * 8;
            bf16x8 a[4], b[4];
            #pragma unroll
            for (int t = 0; t < 4; ++t)
                a[t] = *(const bf16x8*)&As[(wm * 64 + t * 16 + l15) * BK + kb];
            #pragma unroll
            for (int t = 0; t < 4; ++t)
                b[t] = *(const bf16x8*)&Bs[(wn * 64 + t * 16 + l15) * BK + kb];
            #pragma unroll
            for (int mt = 0; mt < 4; ++mt)
                #pragma unroll
                for (int nt = 0; nt < 4; ++nt)
                    acc[mt][nt] = __builtin_amdgcn_mfma_f32_16x16x32_bf16(
                        a[mt], b[nt], acc[mt][nt], 0, 0, 0);
        }
    }
    #pragma unroll
    for (int nt = 0; nt < 4; ++nt) {
        const int col = colBase + wn * 64 + nt * 16 + l15;
        const float tl = t_prev[nt];
        const float bf = Bv[col];
        #pragma unroll
        for (int mt = 0; mt < 4; ++mt) {
            const int row0 = rowBase + wm * 64 + mt * 16 + quad * 4;
            #pragma unroll
            for (int r = 0; r < 4; ++r)
                Y[(size_t)(row0 + r) * N + col] = acc[mt][nt][r] * tl + bf;
        }
    }
}

extern "C" void kernel_launch(void* const* d_in, const int* in_sizes, int n_in,
                              void* d_out, int out_size, void* d_ws, size_t ws_size,
                              hipStream_t stream) {
    const float* X  = (const float*)d_in[0];   // x      (B,S,I)  f32
    const float* W  = (const float*)d_in[1];   // weight (O,I)    f32
    const float* S  = (const float*)d_in[2];   // scales (O,I/G)  f32
    const float* Bv = (const float*)d_in[3];   // bias   (O,)     f32
    float* Y = (float*)d_out;

    const int O = in_sizes[3];                 // 4096
    const int K = in_sizes[1] / O;             // 4096
    const int M = in_sizes[0] / K;             // 8192

    const size_t nX = (size_t)M * K, nW = (size_t)O * K;
    const size_t wsNeeded = (nX + nW) * sizeof(unsigned short);
    const bool shapeOK = (M % 256 == 0) && (O % 256 == 0) && (K % 128 == 0) &&
                         ((K & (K - 1)) == 0);

    if (ws_size >= wsNeeded && shapeOK) {
        unsigned short* Xb = (unsigned short*)d_ws;
        unsigned short* Wb = Xb + nX;
        const int kshift = __builtin_ctz((unsigned)K);
        cvt_f32_bf16<<<(int)(nX >> 11), 256, 0, stream>>>(X, Xb, (long)nX);
        cvt_w_scale_bf16<<<(int)(nW >> 11), 256, 0, stream>>>(
            W, S, Wb, kshift, K >> 7, (long)(nW >> 3));
        gq_gemm256<<<dim3((M >> 8) * (O >> 8)), dim3(512), 0, stream>>>(
            Xb, Wb, Bv, Y, M, O, K);
    } else {
        gq_gemm_f32in<<<dim3((M / BM) * (O / BN)), 256, 0, stream>>>(
            X, W, S, Bv, Y, M, O, K);
    }
}